// Round 9
// baseline (871.314 us; speedup 1.0000x reference)
//
#include <hip/hip_runtime.h>
#include <stdint.h>

#define Bb 2
#define Tt 2048
#define Dd 2048
#define Hh 16
#define HD 128
#define NTOK (Bb*Tt)

typedef _Float16 f16;
typedef unsigned short u16;
typedef __attribute__((ext_vector_type(8))) _Float16 f16x8;
typedef __attribute__((ext_vector_type(4))) _Float16 f16x4;
typedef __attribute__((ext_vector_type(4))) float f32x4;

// async global->LDS, 16B per lane; LDS dest = wave-uniform base + lane*16
__device__ __forceinline__ void gl2lds16(const f16* g, f16* l) {
  __builtin_amdgcn_global_load_lds(
      (const __attribute__((address_space(1))) unsigned int*)(const_cast<f16*>(g)),
      (__attribute__((address_space(3))) unsigned int*)(l),
      16, 0, 0);
}

// ---------------- convert x (fp32 -> f16) + lambda = sigmoid(x @ Wlam) ----------------
__global__ __launch_bounds__(256) void cvtlam_kernel(const float* __restrict__ x,
                                                     const float* __restrict__ Wlam,
                                                     f16* __restrict__ xh,
                                                     float* __restrict__ lamb) {
  const int wid = threadIdx.x >> 6, lane = threadIdx.x & 63;
  const int tok = blockIdx.x * 4 + wid;
  const float* xr = x + (size_t)tok * Dd;
  f16* xo = xh + (size_t)tok * Dd;
  float acc[16] = {};
#pragma unroll
  for (int j = 0; j < 8; ++j) {
    const int k0 = j * 256 + lane * 4;
    float4 v = *(const float4*)(xr + k0);
    f16x4 o;
    o.x = (f16)v.x; o.y = (f16)v.y; o.z = (f16)v.z; o.w = (f16)v.w;
    *(f16x4*)(xo + k0) = o;
    const float xe4[4] = {v.x, v.y, v.z, v.w};
#pragma unroll
    for (int e = 0; e < 4; ++e) {
      const float xe = xe4[e];
      const float4* wr = (const float4*)(Wlam + (size_t)(k0 + e) * Hh);
#pragma unroll
      for (int q = 0; q < 4; ++q) {
        float4 w = wr[q];
        acc[q * 4 + 0] = fmaf(xe, w.x, acc[q * 4 + 0]);
        acc[q * 4 + 1] = fmaf(xe, w.y, acc[q * 4 + 1]);
        acc[q * 4 + 2] = fmaf(xe, w.z, acc[q * 4 + 2]);
        acc[q * 4 + 3] = fmaf(xe, w.w, acc[q * 4 + 3]);
      }
    }
  }
#pragma unroll
  for (int ofs = 32; ofs >= 1; ofs >>= 1)
#pragma unroll
    for (int i = 0; i < 16; ++i) acc[i] += __shfl_xor(acc[i], ofs);
  if (lane == 0) {
#pragma unroll
    for (int i = 0; i < 16; ++i)
      lamb[tok * Hh + i] = 1.f / (1.f + __expf(-acc[i]));
  }
}

// ---------------- transpose + convert the 5 DxD weights ----------------
__global__ void wtrans_kernel(const float* __restrict__ W0, const float* __restrict__ W1,
                              const float* __restrict__ W2, const float* __restrict__ W3,
                              const float* __restrict__ W4, f16* __restrict__ wt) {
  const float* W;
  int z = blockIdx.z;
  if (z == 0) W = W0; else if (z == 1) W = W1; else if (z == 2) W = W2;
  else if (z == 3) W = W3; else W = W4;
  f16* dst = wt + (size_t)z * Dd * Dd;
  __shared__ f16 tile[64][65];
  const int k0 = blockIdx.y * 64, n0 = blockIdx.x * 64;
  const int tr = threadIdx.x >> 6, tc = threadIdx.x & 63;
#pragma unroll
  for (int p = 0; p < 16; ++p) {
    int r = tr + p * 4;
    tile[r][tc] = (f16)W[(size_t)(k0 + r) * Dd + n0 + tc];
  }
  __syncthreads();
#pragma unroll
  for (int p = 0; p < 16; ++p) {
    int r = tr + p * 4;
    dst[(size_t)(n0 + r) * Dd + k0 + tc] = tile[tc][r];
  }
}

// ---------------- GEMM: C = A (M x K) * Bt^T, Bt is (N x K) row-major ----------------
template <int OUTF16>
__global__ __launch_bounds__(256) void gemm_bt_kernel(
    const f16* __restrict__ A, const f16* __restrict__ Bt0,
    unsigned long long bt_stride, void* __restrict__ Cb, unsigned long long c_stride) {
  __shared__ __align__(16) f16 Alds[128 * 32];
  __shared__ __align__(16) f16 Blds[128 * 32];
  const f16* Bt = Bt0 + (size_t)blockIdx.z * bt_stride;
  const int m0 = blockIdx.y * 128, n0 = blockIdx.x * 128;
  const int tid = threadIdx.x, wid = tid >> 6, lane = tid & 63;
  const int quad = lane >> 4, l15 = lane & 15;
  const int srow = lane >> 2, sch = lane & 3;
  const int g = (l15 >> 1) & 3;
  const int koff = (quad ^ g) * 8;
  const int mw = (wid >> 1) * 64, nw = (wid & 1) * 64;
  const int sg = sch ^ ((srow >> 1) & 3);
  f32x4 acc[4][4] = {};
  for (int kk = 0; kk < Dd; kk += 32) {
#pragma unroll
    for (int j = 0; j < 2; ++j) {
      const int c = wid * 2 + j;
      const int row = c * 16 + srow;
      gl2lds16(A + (size_t)(m0 + row) * Dd + kk + sg * 8, &Alds[c * 512]);
      gl2lds16(Bt + (size_t)(n0 + row) * Dd + kk + sg * 8, &Blds[c * 512]);
    }
    __syncthreads();
    f16x8 af[4], bfr[4];
#pragma unroll
    for (int t = 0; t < 4; ++t)
      af[t] = *(const f16x8*)&Alds[(mw + t * 16 + l15) * 32 + koff];
#pragma unroll
    for (int t = 0; t < 4; ++t)
      bfr[t] = *(const f16x8*)&Blds[(nw + t * 16 + l15) * 32 + koff];
#pragma unroll
    for (int mt = 0; mt < 4; ++mt)
#pragma unroll
      for (int nt = 0; nt < 4; ++nt)
        acc[mt][nt] = __builtin_amdgcn_mfma_f32_16x16x32_f16(af[mt], bfr[nt], acc[mt][nt], 0, 0, 0);
    __syncthreads();
  }
  const size_t czoff = (size_t)blockIdx.z * c_stride;
#pragma unroll
  for (int mt = 0; mt < 4; ++mt) {
    const int r0 = m0 + mw + mt * 16 + quad * 4;
#pragma unroll
    for (int r = 0; r < 4; ++r) {
#pragma unroll
      for (int nt = 0; nt < 4; ++nt) {
        const int col = n0 + nw + nt * 16 + l15;
        const float v = acc[mt][nt][r];
        if (OUTF16)
          ((f16*)Cb)[czoff + (size_t)(r0 + r) * Dd + col] = (f16)v;
        else
          ((float*)Cb)[czoff + (size_t)(r0 + r) * Dd + col] = v;
      }
    }
  }
}

// ---------------- transpose V per (b, hkv): (T x 128) -> (128 x T'), key-permuted ----
// Within each 32-key group, storage pos p(u) = quad(u)*8 + half16(u)*4 + (u&3): a b128
// read at fixed d gives the K=32 MFMA B-operand (and P's concat f16x4s give the A side).
__global__ void vtrans_kernel(const f16* __restrict__ vb, f16* __restrict__ vtb) {
  const int z = blockIdx.z;  // b*16 + hkv
  const int b = z >> 4, hv = z & 15;
  const int t0 = blockIdx.x * 64, d0 = blockIdx.y * 64;
  __shared__ f16 tile[64][65];
  const int tr = threadIdx.x >> 6, tc = threadIdx.x & 63;
#pragma unroll
  for (int p = 0; p < 16; ++p) {
    int r = tr + p * 4;
    tile[r][tc] = vb[(size_t)(b * Tt + t0 + r) * Dd + hv * HD + d0 + tc];
  }
  __syncthreads();
  const int u = tc & 31;
  const int tp = (tc & 32) | (((u >> 2) & 3) * 8 + ((u >> 4) & 1) * 4 + (u & 3));
#pragma unroll
  for (int p = 0; p < 16; ++p) {
    int r = tr + p * 4;
    vtb[((size_t)z * HD + d0 + r) * Tt + t0 + tp] = tile[tc][r];
  }
}

// ---------------- causal flash attention ----------------
// 512 threads = 8 waves, 256 q/block (32 q/wave in two 16-q halves). K+V double
// buffered (64 KB shared by 8 waves -> 16 waves/CU); R7-style depth-1 vmcnt pipeline.
// PV uses 16x16x32 (V b128 = K=32 B-operand via storage permutation).
__global__ __launch_bounds__(512, 4) void attn_kernel(
    const f16* __restrict__ q1b, const f16* __restrict__ q2b,
    const f16* __restrict__ kbuf, const f16* __restrict__ vtb,
    f16* __restrict__ yah) {
  __shared__ __align__(16) f16 Klds[2][64 * 128];  // [key][d], chunk16 pos = c ^ (key&7)
  __shared__ __align__(16) f16 Vlds[2][128 * 64];  // [d][key'], chunk16 pos = c ^ (d&7)
  const int bx = blockIdx.x;
  const int qt = (bx & 1) ? (7 - (bx >> 1)) : (bx >> 1);
  const int h = blockIdx.y, b = blockIdx.z;
  const int hkv = h >> 1;
  const f16* qb = (h < Hh) ? q1b : q2b;
  const int hq = h & 15;
  const int tid = threadIdx.x, wid = tid >> 6, lane = tid & 63;
  const int quad = lane >> 4, l15 = lane & 15;
  const int qbase = qt * 256 + wid * 32;      // wave's first q row
  const int ntiles = 4 * qt + 4;
  const f16 qscale = (f16)(0.08838834764831845f * 1.4426950408889634f);

  // Q fragments for both halves (B-operand: n=l15=q, k=quad*8+j), pre-scaled.
  f16x8 qf0[4], qf1[4];
  {
    const f16* qp0 = qb + (size_t)(b * Tt + qbase + l15) * Dd + hq * HD + quad * 8;
    const f16* qp1 = qp0 + (size_t)16 * Dd;
#pragma unroll
    for (int ks = 0; ks < 4; ++ks) { qf0[ks] = *(const f16x8*)(qp0 + ks * 32); qf1[ks] = *(const f16x8*)(qp1 + ks * 32); }
#pragma unroll
    for (int ks = 0; ks < 4; ++ks) { qf0[ks] *= qscale; qf1[ks] *= qscale; }
  }

  // per-thread staging offsets (2 K-slots + 2 V-slots per tile)
  uint32_t koffg[2], voffg[2];
#pragma unroll
  for (int c = 0; c < 2; ++c) {
    const int krow = c * 32 + wid * 4 + (lane >> 4);
    const int kch = (lane & 15) ^ (krow & 7);
    koffg[c] = (uint32_t)((b * Tt + krow) * Dd + hkv * HD + kch * 8);
    const int vrow = c * 64 + wid * 8 + (lane >> 3);
    const int vch = (lane & 7) ^ (vrow & 7);
    voffg[c] = (uint32_t)(((b * 16 + hkv) * HD + vrow) * Tt + vch * 8);
  }

  f32x4 o0[8] = {}, o1[8] = {};
  float m_0 = -3.0e38f, m_1 = -3.0e38f, l_0 = 0.f, l_1 = 0.f;

#define ISSUE_TILE(KT, PAR)                                                          \
  {                                                                                  \
    const uint32_t kshift = (uint32_t)(KT) * 64 * Dd;                                \
    const uint32_t vshift = (uint32_t)(KT) * 64;                                     \
    _Pragma("unroll") for (int c = 0; c < 2; ++c)                                    \
        gl2lds16(kbuf + kshift + koffg[c], &Klds[PAR][(c * 32 + wid * 4) * 128]);    \
    _Pragma("unroll") for (int c = 0; c < 2; ++c)                                    \
        gl2lds16(vtb + vshift + voffg[c], &Vlds[PAR][(c * 64 + wid * 8) * 64]);      \
  }

  ISSUE_TILE(0, 0);
  ISSUE_TILE(1, 1);

  for (int kt = 0; kt < ntiles; ++kt) {
    const int cur = kt & 1;
    // my tile's 4 per-thread loads done; next tile's 4 may stay in flight
    if (kt + 1 < ntiles) asm volatile("s_waitcnt vmcnt(4)\n\ts_barrier" ::: "memory");
    else                 asm volatile("s_waitcnt vmcnt(0)\n\ts_barrier" ::: "memory");

    if (kt * 64 <= qbase + 31) {
      const f16* Kl = &Klds[cur][0];
      const f16* Vl = &Vlds[cur][0];

      // S^T = K . Q^T for both halves, sharing each K fragment
      f32x4 s0[4] = {}, s1[4] = {};
#pragma unroll
      for (int nt = 0; nt < 4; ++nt) {
        const int r = nt * 16 + l15;
#pragma unroll
        for (int ks = 0; ks < 4; ++ks) {
          f16x8 kf = *(const f16x8*)&Kl[r * 128 + (((ks * 4 + quad) ^ (l15 & 7)) << 3)];
          s0[nt] = __builtin_amdgcn_mfma_f32_16x16x32_f16(kf, qf0[ks], s0[nt], 0, 0, 0);
          s1[nt] = __builtin_amdgcn_mfma_f32_16x16x32_f16(kf, qf1[ks], s1[nt], 0, 0, 0);
        }
      }
      // causal mask (only tiles overlapping the wave's q range)
      if (kt * 64 + 63 > qbase) {
        const int q0 = qbase + l15, q1_ = q0 + 16;
#pragma unroll
        for (int nt = 0; nt < 4; ++nt) {
          const int keyb = kt * 64 + nt * 16 + quad * 4;
#pragma unroll
          for (int r = 0; r < 4; ++r) {
            if (keyb + r > q0) s0[nt][r] = -3.0e38f;
            if (keyb + r > q1_) s1[nt][r] = -3.0e38f;
          }
        }
      }
      // online softmax (exp2 space), both halves interleaved for ILP
      float tm0 = s0[0][0], tm1 = s1[0][0];
#pragma unroll
      for (int nt = 0; nt < 4; ++nt)
#pragma unroll
        for (int r = 0; r < 4; ++r) { tm0 = fmaxf(tm0, s0[nt][r]); tm1 = fmaxf(tm1, s1[nt][r]); }
      tm0 = fmaxf(tm0, __shfl_xor(tm0, 16)); tm1 = fmaxf(tm1, __shfl_xor(tm1, 16));
      tm0 = fmaxf(tm0, __shfl_xor(tm0, 32)); tm1 = fmaxf(tm1, __shfl_xor(tm1, 32));
      const float mo0 = m_0, mo1 = m_1;
      m_0 = fmaxf(m_0, tm0); m_1 = fmaxf(m_1, tm1);
      float rs0 = 0.f, rs1 = 0.f;
      f16x4 pf0[4], pf1[4];
#pragma unroll
      for (int nt = 0; nt < 4; ++nt) {
        float a0 = exp2f(s0[nt][0] - m_0), a1 = exp2f(s0[nt][1] - m_0);
        float a2 = exp2f(s0[nt][2] - m_0), a3 = exp2f(s0[nt][3] - m_0);
        float b0 = exp2f(s1[nt][0] - m_1), b1 = exp2f(s1[nt][1] - m_1);
        float b2 = exp2f(s1[nt][2] - m_1), b3 = exp2f(s1[nt][3] - m_1);
        rs0 += (a0 + a1) + (a2 + a3);
        rs1 += (b0 + b1) + (b2 + b3);
        pf0[nt].x = (f16)a0; pf0[nt].y = (f16)a1; pf0[nt].z = (f16)a2; pf0[nt].w = (f16)a3;
        pf1[nt].x = (f16)b0; pf1[nt].y = (f16)b1; pf1[nt].z = (f16)b2; pf1[nt].w = (f16)b3;
      }
      rs0 += __shfl_xor(rs0, 16); rs1 += __shfl_xor(rs1, 16);
      rs0 += __shfl_xor(rs0, 32); rs1 += __shfl_xor(rs1, 32);
      if (__ballot((m_0 > mo0) | (m_1 > mo1))) {
        const float al0 = exp2f(mo0 - m_0), al1 = exp2f(mo1 - m_1);
        l_0 *= al0; l_1 *= al1;
        float ar0[4], ar1[4];
#pragma unroll
        for (int r = 0; r < 4; ++r) { ar0[r] = __shfl(al0, quad * 4 + r); ar1[r] = __shfl(al1, quad * 4 + r); }
#pragma unroll
        for (int n2 = 0; n2 < 8; ++n2)
#pragma unroll
          for (int r = 0; r < 4; ++r) { o0[n2][r] *= ar0[r]; o1[n2][r] *= ar1[r]; }
      }
      l_0 += rs0; l_1 += rs1;
      // O += P.V : K=32 MFMA; V b128 read IS the B-operand, P concat IS the A-operand
#pragma unroll
      for (int g = 0; g < 2; ++g) {
        const f16x8 pf8_0 = __builtin_shufflevector(pf0[2 * g], pf0[2 * g + 1], 0, 1, 2, 3, 4, 5, 6, 7);
        const f16x8 pf8_1 = __builtin_shufflevector(pf1[2 * g], pf1[2 * g + 1], 0, 1, 2, 3, 4, 5, 6, 7);
#pragma unroll
        for (int n2 = 0; n2 < 8; ++n2) {
          const int d_ = n2 * 16 + l15;
          f16x8 vf = *(const f16x8*)&Vl[d_ * 64 + (((g * 4 + quad) ^ (l15 & 7)) << 3)];
          o0[n2] = __builtin_amdgcn_mfma_f32_16x16x32_f16(pf8_0, vf, o0[n2], 0, 0, 0);
          o1[n2] = __builtin_amdgcn_mfma_f32_16x16x32_f16(pf8_1, vf, o1[n2], 0, 0, 0);
        }
      }
    }
    // all waves done reading buf[cur] -> safe to refill with tile kt+2
    asm volatile("s_waitcnt lgkmcnt(0)\n\ts_barrier" ::: "memory");
    if (kt + 2 < ntiles) ISSUE_TILE(kt + 2, cur);
  }
#undef ISSUE_TILE

  // epilogue: l keyed by q=l15 per half; O rows are quad*4+r
  float lr0[4], lr1[4];
#pragma unroll
  for (int r = 0; r < 4; ++r) { lr0[r] = __shfl(l_0, quad * 4 + r); lr1[r] = __shfl(l_1, quad * 4 + r); }
#pragma unroll
  for (int r = 0; r < 4; ++r) {
    const float i0 = 1.0f / lr0[r], i1 = 1.0f / lr1[r];
    const int row0 = qbase + quad * 4 + r;
    f16* d0_ = yah + ((size_t)(b * 32 + h) * Tt + row0) * HD;
    f16* d1_ = d0_ + (size_t)16 * HD;
#pragma unroll
    for (int n2 = 0; n2 < 8; ++n2) {
      d0_[n2 * 16 + l15] = (f16)(o0[n2][r] * i0);
      d1_[n2 * 16 + l15] = (f16)(o1[n2][r] * i1);
    }
  }
}

// ---------------- y = y1 - lam*y2, to f16 token-major ----------------
__global__ void combine_kernel(const f16* __restrict__ yah, const float* __restrict__ lamb,
                               f16* __restrict__ ybf) {
  const int n4 = NTOK * Dd / 4;
  int i = blockIdx.x * 256 + threadIdx.x;
  const int stride = gridDim.x * 256;
  for (; i < n4; i += stride) {
    const int e0 = i * 4;
    const int dc = e0 & 127;
    const int hh = (e0 >> 7) & 15;
    const int tt = (e0 >> 11) & 2047;
    const int bb = e0 >> 22;
    const size_t base1 = ((size_t)(bb * 32 + hh) * Tt + tt) * HD + dc;
    const size_t base2 = ((size_t)(bb * 32 + 16 + hh) * Tt + tt) * HD + dc;
    f16x4 y1 = *(const f16x4*)(yah + base1);
    f16x4 y2 = *(const f16x4*)(yah + base2);
    const float lam = lamb[(bb * Tt + tt) * Hh + hh];
    f16x4 o;
    o.x = (f16)((float)y1.x - lam * (float)y2.x);
    o.y = (f16)((float)y1.y - lam * (float)y2.y);
    o.z = (f16)((float)y1.z - lam * (float)y2.z);
    o.w = (f16)((float)y1.w - lam * (float)y2.w);
    *(f16x4*)(ybf + e0) = o;
  }
}

extern "C" void kernel_launch(void* const* d_in, const int* in_sizes, int n_in,
                              void* d_out, int out_size, void* d_ws, size_t ws_size,
                              hipStream_t stream) {
  const float* x    = (const float*)d_in[0];
  const float* Wq1  = (const float*)d_in[1];
  const float* Wq2  = (const float*)d_in[2];
  const float* Wk   = (const float*)d_in[3];
  const float* Wv   = (const float*)d_in[4];
  const float* Wlam = (const float*)d_in[5];
  const float* Wo   = (const float*)d_in[6];

  f16* xbf = (f16*)d_ws;
  f16* wt  = xbf + (size_t)NTOK * Dd;
  f16* q1b = wt + 5ull * Dd * Dd;
  f16* q2b = q1b + (size_t)NTOK * Dd;
  f16* kbf = q2b + (size_t)NTOK * Dd;
  f16* vbf = kbf + (size_t)NTOK * Dd;
  f16* vtb = vbf + (size_t)NTOK * Dd;
  float* lamb = (float*)(vtb + (size_t)NTOK * Dd);
  f16* yah = (f16*)(lamb + (size_t)NTOK * Hh);   // B*32*T*128 f16
  f16* ybf = xbf;

  cvtlam_kernel<<<dim3(NTOK / 4), dim3(256), 0, stream>>>(x, Wlam, xbf, lamb);
  wtrans_kernel<<<dim3(32, 32, 5), dim3(256), 0, stream>>>(Wq1, Wq2, Wk, Wv, Wo, wt);
  gemm_bt_kernel<1><<<dim3(16, 32, 4), dim3(256), 0, stream>>>(
      xbf, wt, (unsigned long long)Dd * Dd, (void*)q1b, (unsigned long long)NTOK * Dd);
  vtrans_kernel<<<dim3(32, 2, 32), dim3(256), 0, stream>>>(vbf, vtb);
  attn_kernel<<<dim3(8, 32, 2), dim3(512), 0, stream>>>(q1b, q2b, kbf, vtb, yah);
  combine_kernel<<<dim3(2048), dim3(256), 0, stream>>>(yah, lamb, ybf);
  gemm_bt_kernel<0><<<dim3(16, 32, 1), dim3(256), 0, stream>>>(
      ybf, wt + 4ull * Dd * Dd, 0ull, d_out, 0ull);
}

// Round 10
// 626.484 us; speedup vs baseline: 1.3908x; 1.3908x over previous
//
#include <hip/hip_runtime.h>
#include <stdint.h>

#define Bb 2
#define Tt 2048
#define Dd 2048
#define Hh 16
#define HD 128
#define NTOK (Bb*Tt)

typedef _Float16 f16;
typedef unsigned short u16;
typedef __attribute__((ext_vector_type(8))) _Float16 f16x8;
typedef __attribute__((ext_vector_type(4))) _Float16 f16x4;
typedef __attribute__((ext_vector_type(4))) float f32x4;

// async global->LDS, 16B per lane; LDS dest = wave-uniform base + lane*16
__device__ __forceinline__ void gl2lds16(const f16* g, f16* l) {
  __builtin_amdgcn_global_load_lds(
      (const __attribute__((address_space(1))) unsigned int*)(const_cast<f16*>(g)),
      (__attribute__((address_space(3))) unsigned int*)(l),
      16, 0, 0);
}

// ---------------- convert x (fp32 -> f16) + lambda = sigmoid(x @ Wlam) ----------------
__global__ __launch_bounds__(256) void cvtlam_kernel(const float* __restrict__ x,
                                                     const float* __restrict__ Wlam,
                                                     f16* __restrict__ xh,
                                                     float* __restrict__ lamb) {
  const int wid = threadIdx.x >> 6, lane = threadIdx.x & 63;
  const int tok = blockIdx.x * 4 + wid;
  const float* xr = x + (size_t)tok * Dd;
  f16* xo = xh + (size_t)tok * Dd;
  float acc[16] = {};
#pragma unroll
  for (int j = 0; j < 8; ++j) {
    const int k0 = j * 256 + lane * 4;
    float4 v = *(const float4*)(xr + k0);
    f16x4 o;
    o.x = (f16)v.x; o.y = (f16)v.y; o.z = (f16)v.z; o.w = (f16)v.w;
    *(f16x4*)(xo + k0) = o;
    const float xe4[4] = {v.x, v.y, v.z, v.w};
#pragma unroll
    for (int e = 0; e < 4; ++e) {
      const float xe = xe4[e];
      const float4* wr = (const float4*)(Wlam + (size_t)(k0 + e) * Hh);
#pragma unroll
      for (int q = 0; q < 4; ++q) {
        float4 w = wr[q];
        acc[q * 4 + 0] = fmaf(xe, w.x, acc[q * 4 + 0]);
        acc[q * 4 + 1] = fmaf(xe, w.y, acc[q * 4 + 1]);
        acc[q * 4 + 2] = fmaf(xe, w.z, acc[q * 4 + 2]);
        acc[q * 4 + 3] = fmaf(xe, w.w, acc[q * 4 + 3]);
      }
    }
  }
#pragma unroll
  for (int ofs = 32; ofs >= 1; ofs >>= 1)
#pragma unroll
    for (int i = 0; i < 16; ++i) acc[i] += __shfl_xor(acc[i], ofs);
  if (lane == 0) {
#pragma unroll
    for (int i = 0; i < 16; ++i)
      lamb[tok * Hh + i] = 1.f / (1.f + __expf(-acc[i]));
  }
}

// ---------------- transpose + convert the 5 DxD weights ----------------
__global__ void wtrans_kernel(const float* __restrict__ W0, const float* __restrict__ W1,
                              const float* __restrict__ W2, const float* __restrict__ W3,
                              const float* __restrict__ W4, f16* __restrict__ wt) {
  const float* W;
  int z = blockIdx.z;
  if (z == 0) W = W0; else if (z == 1) W = W1; else if (z == 2) W = W2;
  else if (z == 3) W = W3; else W = W4;
  f16* dst = wt + (size_t)z * Dd * Dd;
  __shared__ f16 tile[64][65];
  const int k0 = blockIdx.y * 64, n0 = blockIdx.x * 64;
  const int tr = threadIdx.x >> 6, tc = threadIdx.x & 63;
#pragma unroll
  for (int p = 0; p < 16; ++p) {
    int r = tr + p * 4;
    tile[r][tc] = (f16)W[(size_t)(k0 + r) * Dd + n0 + tc];
  }
  __syncthreads();
#pragma unroll
  for (int p = 0; p < 16; ++p) {
    int r = tr + p * 4;
    dst[(size_t)(n0 + r) * Dd + k0 + tc] = tile[tc][r];
  }
}

// ---------------- GEMM: C = A (M x K) * Bt^T, Bt is (N x K) row-major ----------------
template <int OUTF16>
__global__ __launch_bounds__(256) void gemm_bt_kernel(
    const f16* __restrict__ A, const f16* __restrict__ Bt0,
    unsigned long long bt_stride, void* __restrict__ Cb, unsigned long long c_stride) {
  __shared__ __align__(16) f16 Alds[128 * 32];
  __shared__ __align__(16) f16 Blds[128 * 32];
  const f16* Bt = Bt0 + (size_t)blockIdx.z * bt_stride;
  const int m0 = blockIdx.y * 128, n0 = blockIdx.x * 128;
  const int tid = threadIdx.x, wid = tid >> 6, lane = tid & 63;
  const int quad = lane >> 4, l15 = lane & 15;
  const int srow = lane >> 2, sch = lane & 3;
  const int g = (l15 >> 1) & 3;
  const int koff = (quad ^ g) * 8;
  const int mw = (wid >> 1) * 64, nw = (wid & 1) * 64;
  const int sg = sch ^ ((srow >> 1) & 3);
  f32x4 acc[4][4] = {};
  for (int kk = 0; kk < Dd; kk += 32) {
#pragma unroll
    for (int j = 0; j < 2; ++j) {
      const int c = wid * 2 + j;
      const int row = c * 16 + srow;
      gl2lds16(A + (size_t)(m0 + row) * Dd + kk + sg * 8, &Alds[c * 512]);
      gl2lds16(Bt + (size_t)(n0 + row) * Dd + kk + sg * 8, &Blds[c * 512]);
    }
    __syncthreads();
    f16x8 af[4], bfr[4];
#pragma unroll
    for (int t = 0; t < 4; ++t)
      af[t] = *(const f16x8*)&Alds[(mw + t * 16 + l15) * 32 + koff];
#pragma unroll
    for (int t = 0; t < 4; ++t)
      bfr[t] = *(const f16x8*)&Blds[(nw + t * 16 + l15) * 32 + koff];
#pragma unroll
    for (int mt = 0; mt < 4; ++mt)
#pragma unroll
      for (int nt = 0; nt < 4; ++nt)
        acc[mt][nt] = __builtin_amdgcn_mfma_f32_16x16x32_f16(af[mt], bfr[nt], acc[mt][nt], 0, 0, 0);
    __syncthreads();
  }
  const size_t czoff = (size_t)blockIdx.z * c_stride;
#pragma unroll
  for (int mt = 0; mt < 4; ++mt) {
    const int r0 = m0 + mw + mt * 16 + quad * 4;
#pragma unroll
    for (int r = 0; r < 4; ++r) {
#pragma unroll
      for (int nt = 0; nt < 4; ++nt) {
        const int col = n0 + nw + nt * 16 + l15;
        const float v = acc[mt][nt][r];
        if (OUTF16)
          ((f16*)Cb)[czoff + (size_t)(r0 + r) * Dd + col] = (f16)v;
        else
          ((float*)Cb)[czoff + (size_t)(r0 + r) * Dd + col] = v;
      }
    }
  }
}

// ---------------- transpose V per (b, hkv): (T x 128) -> (128 x T'), key-permuted ----
// Within each 32-key group, storage pos p(u) = quad(u)*8 + half16(u)*4 + (u&3): a b128
// read at fixed d gives the K=32 MFMA B-operand (and P's concat f16x4s give the A side).
__global__ void vtrans_kernel(const f16* __restrict__ vb, f16* __restrict__ vtb) {
  const int z = blockIdx.z;  // b*16 + hkv
  const int b = z >> 4, hv = z & 15;
  const int t0 = blockIdx.x * 64, d0 = blockIdx.y * 64;
  __shared__ f16 tile[64][65];
  const int tr = threadIdx.x >> 6, tc = threadIdx.x & 63;
#pragma unroll
  for (int p = 0; p < 16; ++p) {
    int r = tr + p * 4;
    tile[r][tc] = vb[(size_t)(b * Tt + t0 + r) * Dd + hv * HD + d0 + tc];
  }
  __syncthreads();
  const int u = tc & 31;
  const int tp = (tc & 32) | (((u >> 2) & 3) * 8 + ((u >> 4) & 1) * 4 + (u & 3));
#pragma unroll
  for (int p = 0; p < 16; ++p) {
    int r = tr + p * 4;
    vtb[((size_t)z * HD + d0 + r) * Tt + t0 + tp] = tile[tc][r];
  }
}

// ---------------- causal flash attention ----------------
// R7 verified config: 256 threads = 4 waves, 32 q/wave, K+V double-buffered 64 KB,
// depth-1 vmcnt(8) pipeline, launch_bounds(256,2) -> 96 VGPR no spill.
// Delta vs R7: PV uses one 16x16x32 MFMA per V b128 read (P concat = A-operand).
__global__ __launch_bounds__(256, 2) void attn_kernel(
    const f16* __restrict__ q1b, const f16* __restrict__ q2b,
    const f16* __restrict__ kbuf, const f16* __restrict__ vtb,
    f16* __restrict__ yah) {
  __shared__ __align__(16) f16 Klds[2][64 * 128];  // [key][d], chunk16 pos = c ^ (key&7)
  __shared__ __align__(16) f16 Vlds[2][128 * 64];  // [d][key'], chunk16 pos = c ^ (d&7)
  const int bx = blockIdx.x;
  const int qt = (bx & 1) ? (15 - (bx >> 1)) : (bx >> 1);
  const int h = blockIdx.y, b = blockIdx.z;
  const int hkv = h >> 1;
  const f16* qb = (h < Hh) ? q1b : q2b;
  const int hq = h & 15;
  const int tid = threadIdx.x, wid = tid >> 6, lane = tid & 63;
  const int quad = lane >> 4, l15 = lane & 15;
  const int qbase = qt * 128 + wid * 32;      // wave's first q row
  const int ntiles = 2 * qt + 2;
  const f16 qscale = (f16)(0.08838834764831845f * 1.4426950408889634f);

  // Q fragments for both halves (B-operand: n=l15=q, k=quad*8+j), pre-scaled.
  f16x8 qf0[4], qf1[4];
  {
    const f16* qp0 = qb + (size_t)(b * Tt + qbase + l15) * Dd + hq * HD + quad * 8;
    const f16* qp1 = qp0 + (size_t)16 * Dd;
#pragma unroll
    for (int ks = 0; ks < 4; ++ks) { qf0[ks] = *(const f16x8*)(qp0 + ks * 32); qf1[ks] = *(const f16x8*)(qp1 + ks * 32); }
#pragma unroll
    for (int ks = 0; ks < 4; ++ks) { qf0[ks] *= qscale; qf1[ks] *= qscale; }
  }

  // per-lane staging offsets (32-bit element units), kt-invariant parts
  uint32_t koffg[4], voffg[4];
#pragma unroll
  for (int p = 0; p < 4; ++p) {
    const int krow = wid * 16 + p * 4 + (lane >> 4);
    const int kch = (lane & 15) ^ (krow & 7);
    koffg[p] = (uint32_t)((b * Tt + krow) * Dd + hkv * HD + kch * 8);
    const int vrow = wid * 32 + p * 8 + (lane >> 3);
    const int vch = (lane & 7) ^ (vrow & 7);
    voffg[p] = (uint32_t)(((b * 16 + hkv) * HD + vrow) * Tt + vch * 8);
  }

  f32x4 o0[8] = {}, o1[8] = {};
  float m_0 = -3.0e38f, m_1 = -3.0e38f, l_0 = 0.f, l_1 = 0.f;

#define ISSUE_TILE(KT, PAR)                                                        \
  {                                                                                \
    const uint32_t kshift = (uint32_t)(KT) * 64 * Dd;                              \
    const uint32_t vshift = (uint32_t)(KT) * 64;                                   \
    _Pragma("unroll") for (int p = 0; p < 4; ++p)                                  \
        gl2lds16(kbuf + kshift + koffg[p], &Klds[PAR][(wid * 16 + p * 4) * 128]);  \
    _Pragma("unroll") for (int p = 0; p < 4; ++p)                                  \
        gl2lds16(vtb + vshift + voffg[p], &Vlds[PAR][(wid * 32 + p * 8) * 64]);    \
  }

  ISSUE_TILE(0, 0);
  ISSUE_TILE(1, 1);

  for (int kt = 0; kt < ntiles; ++kt) {
    const int cur = kt & 1;
    if (kt + 1 < ntiles) asm volatile("s_waitcnt vmcnt(8)\n\ts_barrier" ::: "memory");
    else                 asm volatile("s_waitcnt vmcnt(0)\n\ts_barrier" ::: "memory");

    // skip compute when the whole tile is above this wave's q range
    if (kt * 64 <= qbase + 31) {
      const f16* Kl = &Klds[cur][0];
      const f16* Vl = &Vlds[cur][0];

      // S^T = K . Q^T for both halves, sharing each K fragment
      f32x4 s0[4] = {}, s1[4] = {};
#pragma unroll
      for (int nt = 0; nt < 4; ++nt) {
        const int r = nt * 16 + l15;
#pragma unroll
        for (int ks = 0; ks < 4; ++ks) {
          f16x8 kf = *(const f16x8*)&Kl[r * 128 + (((ks * 4 + quad) ^ (l15 & 7)) << 3)];
          s0[nt] = __builtin_amdgcn_mfma_f32_16x16x32_f16(kf, qf0[ks], s0[nt], 0, 0, 0);
          s1[nt] = __builtin_amdgcn_mfma_f32_16x16x32_f16(kf, qf1[ks], s1[nt], 0, 0, 0);
        }
      }
      // causal mask (only tiles overlapping the wave's q range)
      if (kt * 64 + 63 > qbase) {
        const int q0 = qbase + l15, q1_ = q0 + 16;
#pragma unroll
        for (int nt = 0; nt < 4; ++nt) {
          const int keyb = kt * 64 + nt * 16 + quad * 4;
#pragma unroll
          for (int r = 0; r < 4; ++r) {
            if (keyb + r > q0) s0[nt][r] = -3.0e38f;
            if (keyb + r > q1_) s1[nt][r] = -3.0e38f;
          }
        }
      }
      // online softmax (exp2 space), both halves interleaved for ILP
      float tm0 = s0[0][0], tm1 = s1[0][0];
#pragma unroll
      for (int nt = 0; nt < 4; ++nt)
#pragma unroll
        for (int r = 0; r < 4; ++r) { tm0 = fmaxf(tm0, s0[nt][r]); tm1 = fmaxf(tm1, s1[nt][r]); }
      tm0 = fmaxf(tm0, __shfl_xor(tm0, 16)); tm1 = fmaxf(tm1, __shfl_xor(tm1, 16));
      tm0 = fmaxf(tm0, __shfl_xor(tm0, 32)); tm1 = fmaxf(tm1, __shfl_xor(tm1, 32));
      const float mo0 = m_0, mo1 = m_1;
      m_0 = fmaxf(m_0, tm0); m_1 = fmaxf(m_1, tm1);
      float rs0 = 0.f, rs1 = 0.f;
      f16x4 pf0[4], pf1[4];
#pragma unroll
      for (int nt = 0; nt < 4; ++nt) {
        float a0 = exp2f(s0[nt][0] - m_0), a1 = exp2f(s0[nt][1] - m_0);
        float a2 = exp2f(s0[nt][2] - m_0), a3 = exp2f(s0[nt][3] - m_0);
        float b0 = exp2f(s1[nt][0] - m_1), b1 = exp2f(s1[nt][1] - m_1);
        float b2 = exp2f(s1[nt][2] - m_1), b3 = exp2f(s1[nt][3] - m_1);
        rs0 += (a0 + a1) + (a2 + a3);
        rs1 += (b0 + b1) + (b2 + b3);
        pf0[nt].x = (f16)a0; pf0[nt].y = (f16)a1; pf0[nt].z = (f16)a2; pf0[nt].w = (f16)a3;
        pf1[nt].x = (f16)b0; pf1[nt].y = (f16)b1; pf1[nt].z = (f16)b2; pf1[nt].w = (f16)b3;
      }
      rs0 += __shfl_xor(rs0, 16); rs1 += __shfl_xor(rs1, 16);
      rs0 += __shfl_xor(rs0, 32); rs1 += __shfl_xor(rs1, 32);
      if (__ballot((m_0 > mo0) | (m_1 > mo1))) {
        const float al0 = exp2f(mo0 - m_0), al1 = exp2f(mo1 - m_1);
        l_0 *= al0; l_1 *= al1;
        float ar0[4], ar1[4];
#pragma unroll
        for (int r = 0; r < 4; ++r) { ar0[r] = __shfl(al0, quad * 4 + r); ar1[r] = __shfl(al1, quad * 4 + r); }
#pragma unroll
        for (int n2 = 0; n2 < 8; ++n2)
#pragma unroll
          for (int r = 0; r < 4; ++r) { o0[n2][r] *= ar0[r]; o1[n2][r] *= ar1[r]; }
      }
      l_0 += rs0; l_1 += rs1;
      // O += P.V : one b128 V read = K=32 B-operand; P concat = A-operand
#pragma unroll
      for (int g = 0; g < 2; ++g) {
        const f16x8 pf8_0 = __builtin_shufflevector(pf0[2 * g], pf0[2 * g + 1], 0, 1, 2, 3, 4, 5, 6, 7);
        const f16x8 pf8_1 = __builtin_shufflevector(pf1[2 * g], pf1[2 * g + 1], 0, 1, 2, 3, 4, 5, 6, 7);
#pragma unroll
        for (int n2 = 0; n2 < 8; ++n2) {
          const int d_ = n2 * 16 + l15;
          f16x8 vf = *(const f16x8*)&Vl[d_ * 64 + (((g * 4 + quad) ^ (l15 & 7)) << 3)];
          o0[n2] = __builtin_amdgcn_mfma_f32_16x16x32_f16(pf8_0, vf, o0[n2], 0, 0, 0);
          o1[n2] = __builtin_amdgcn_mfma_f32_16x16x32_f16(pf8_1, vf, o1[n2], 0, 0, 0);
        }
      }
    }
    // all waves done reading buf[cur] -> safe to refill with tile kt+2
    asm volatile("s_waitcnt lgkmcnt(0)\n\ts_barrier" ::: "memory");
    if (kt + 2 < ntiles) ISSUE_TILE(kt + 2, cur);
  }
#undef ISSUE_TILE

  // epilogue: l keyed by q=l15 per half; O rows are quad*4+r
  float lr0[4], lr1[4];
#pragma unroll
  for (int r = 0; r < 4; ++r) { lr0[r] = __shfl(l_0, quad * 4 + r); lr1[r] = __shfl(l_1, quad * 4 + r); }
#pragma unroll
  for (int r = 0; r < 4; ++r) {
    const float i0 = 1.0f / lr0[r], i1 = 1.0f / lr1[r];
    const int row0 = qbase + quad * 4 + r;
    f16* d0_ = yah + ((size_t)(b * 32 + h) * Tt + row0) * HD;
    f16* d1_ = d0_ + (size_t)16 * HD;
#pragma unroll
    for (int n2 = 0; n2 < 8; ++n2) {
      d0_[n2 * 16 + l15] = (f16)(o0[n2][r] * i0);
      d1_[n2 * 16 + l15] = (f16)(o1[n2][r] * i1);
    }
  }
}

// ---------------- y = y1 - lam*y2, to f16 token-major ----------------
__global__ void combine_kernel(const f16* __restrict__ yah, const float* __restrict__ lamb,
                               f16* __restrict__ ybf) {
  const int n4 = NTOK * Dd / 4;
  int i = blockIdx.x * 256 + threadIdx.x;
  const int stride = gridDim.x * 256;
  for (; i < n4; i += stride) {
    const int e0 = i * 4;
    const int dc = e0 & 127;
    const int hh = (e0 >> 7) & 15;
    const int tt = (e0 >> 11) & 2047;
    const int bb = e0 >> 22;
    const size_t base1 = ((size_t)(bb * 32 + hh) * Tt + tt) * HD + dc;
    const size_t base2 = ((size_t)(bb * 32 + 16 + hh) * Tt + tt) * HD + dc;
    f16x4 y1 = *(const f16x4*)(yah + base1);
    f16x4 y2 = *(const f16x4*)(yah + base2);
    const float lam = lamb[(bb * Tt + tt) * Hh + hh];
    f16x4 o;
    o.x = (f16)((float)y1.x - lam * (float)y2.x);
    o.y = (f16)((float)y1.y - lam * (float)y2.y);
    o.z = (f16)((float)y1.z - lam * (float)y2.z);
    o.w = (f16)((float)y1.w - lam * (float)y2.w);
    *(f16x4*)(ybf + e0) = o;
  }
}

extern "C" void kernel_launch(void* const* d_in, const int* in_sizes, int n_in,
                              void* d_out, int out_size, void* d_ws, size_t ws_size,
                              hipStream_t stream) {
  const float* x    = (const float*)d_in[0];
  const float* Wq1  = (const float*)d_in[1];
  const float* Wq2  = (const float*)d_in[2];
  const float* Wk   = (const float*)d_in[3];
  const float* Wv   = (const float*)d_in[4];
  const float* Wlam = (const float*)d_in[5];
  const float* Wo   = (const float*)d_in[6];

  f16* xbf = (f16*)d_ws;
  f16* wt  = xbf + (size_t)NTOK * Dd;
  f16* q1b = wt + 5ull * Dd * Dd;
  f16* q2b = q1b + (size_t)NTOK * Dd;
  f16* kbf = q2b + (size_t)NTOK * Dd;
  f16* vbf = kbf + (size_t)NTOK * Dd;
  f16* vtb = vbf + (size_t)NTOK * Dd;
  float* lamb = (float*)(vtb + (size_t)NTOK * Dd);
  f16* yah = (f16*)(lamb + (size_t)NTOK * Hh);   // B*32*T*128 f16
  f16* ybf = xbf;

  cvtlam_kernel<<<dim3(NTOK / 4), dim3(256), 0, stream>>>(x, Wlam, xbf, lamb);
  wtrans_kernel<<<dim3(32, 32, 5), dim3(256), 0, stream>>>(Wq1, Wq2, Wk, Wv, Wo, wt);
  gemm_bt_kernel<1><<<dim3(16, 32, 4), dim3(256), 0, stream>>>(
      xbf, wt, (unsigned long long)Dd * Dd, (void*)q1b, (unsigned long long)NTOK * Dd);
  vtrans_kernel<<<dim3(32, 2, 32), dim3(256), 0, stream>>>(vbf, vtb);
  attn_kernel<<<dim3(16, 32, 2), dim3(256), 0, stream>>>(q1b, q2b, kbf, vtb, yah);
  combine_kernel<<<dim3(2048), dim3(256), 0, stream>>>(yah, lamb, ybf);
  gemm_bt_kernel<0><<<dim3(16, 32, 1), dim3(256), 0, stream>>>(
      ybf, wt + 4ull * Dd * Dd, 0ull, d_out, 0ull);
}